// Round 2
// baseline (448.767 us; speedup 1.0000x reference)
//
#include <hip/hip_runtime.h>

// CKKS-style polynomial softmax over rows of 2048 fp32. x: [16, 2048, 2048].
// One WAVE per row, 4 rows per wave, software-pipelined:
//   - row r+1's 8 x global_load_dwordx4 are issued BEFORE row r's compute,
//     so loads stay in flight under the Horner + shuffle-reduce chain
//     (compiler emits s_waitcnt vmcnt(8), not vmcnt(0)).
//   - no LDS, no __syncthreads: row-sum is an in-wave shfl_xor butterfly.
//   - plain (cached) loads: input is ~L3-sized and reused across bench
//     iterations; nontemporal STORES only, so the write stream doesn't
//     evict the input from L2/L3.

typedef float v4f __attribute__((ext_vector_type(4)));

#define ROWLEN          2048
#define TPB             256
#define WAVES_PER_BLOCK 4
#define ROWS_PER_WAVE   4
// rows per block = 16; grid = 32768/16 = 2048 blocks.

__global__ __launch_bounds__(TPB) void ckks_softmax_kernel(
    const float* __restrict__ x,
    const float* __restrict__ exp_c,   // 9 coeffs, power basis
    const float* __restrict__ inv_c,   // 5 coeffs
    const int*   __restrict__ iters_p, // single int (==3)
    float* __restrict__ out)
{
    const int lane = threadIdx.x & 63;
    const int wave = threadIdx.x >> 6;
    const size_t gwave = (size_t)blockIdx.x * WAVES_PER_BLOCK + wave;
    const size_t row0  = gwave * ROWS_PER_WAVE;

    // Uniform coefficient loads -> SGPRs.
    const float c0 = exp_c[0], c1 = exp_c[1], c2 = exp_c[2], c3 = exp_c[3],
                c4 = exp_c[4], c5 = exp_c[5], c6 = exp_c[6], c7 = exp_c[7],
                c8 = exp_c[8];
    const float i0 = inv_c[0], i1 = inv_c[1], i2 = inv_c[2], i3 = inv_c[3],
                i4 = inv_c[4];
    const int iters = *iters_p;

    auto horner8 = [&](float t) -> float {
        float acc = c8;
        acc = fmaf(acc, t, c7);
        acc = fmaf(acc, t, c6);
        acc = fmaf(acc, t, c5);
        acc = fmaf(acc, t, c4);
        acc = fmaf(acc, t, c3);
        acc = fmaf(acc, t, c2);
        acc = fmaf(acc, t, c1);
        acc = fmaf(acc, t, c0);
        return acc;
    };

    v4f cur[8], nxt[8];

    // Prologue: load row0.
    {
        const v4f* __restrict__ src = (const v4f*)(x + row0 * ROWLEN);
        #pragma unroll
        for (int k = 0; k < 8; ++k)
            cur[k] = src[lane + 64 * k];
    }

    #pragma unroll
    for (int r = 0; r < ROWS_PER_WAVE; ++r) {
        // Prefetch next row FIRST: its loads ride out under this row's compute.
        if (r + 1 < ROWS_PER_WAVE) {
            const v4f* __restrict__ srcn =
                (const v4f*)(x + (row0 + (size_t)(r + 1)) * ROWLEN);
            #pragma unroll
            for (int k = 0; k < 8; ++k)
                nxt[k] = srcn[lane + 64 * k];
        }

        // e = poly_exp(x); keep e resident in cur[]; shallow partial-sum tree.
        v4f acc4 = {0.0f, 0.0f, 0.0f, 0.0f};
        #pragma unroll
        for (int k = 0; k < 8; ++k) {
            v4f e;
            e.x = horner8(cur[k].x);
            e.y = horner8(cur[k].y);
            e.z = horner8(cur[k].z);
            e.w = horner8(cur[k].w);
            cur[k] = e;
            acc4 += e;
        }
        float s = (acc4.x + acc4.y) + (acc4.z + acc4.w);

        // In-wave butterfly: every lane ends with the full row sum.
        #pragma unroll
        for (int off = 32; off > 0; off >>= 1)
            s += __shfl_xor(s, off, 64);

        // Initial reciprocal guess (degree-4 Horner), redundant per lane.
        float y = i4;
        y = fmaf(y, s, i3);
        y = fmaf(y, s, i2);
        y = fmaf(y, s, i1);
        y = fmaf(y, s, i0);

        // Newton-Raphson: y <- y * (2 - s*y).
        for (int i = 0; i < iters; ++i)
            y = y * (2.0f - s * y);

        // Scale and stream out (nontemporal: never re-read by the kernel,
        // keep the write stream out of L2/L3 so the input stays resident).
        v4f* __restrict__ dst = (v4f*)(out + (row0 + (size_t)r) * ROWLEN);
        #pragma unroll
        for (int k = 0; k < 8; ++k) {
            v4f e = cur[k] * y;
            __builtin_nontemporal_store(e, &dst[lane + 64 * k]);
        }

        // Rotate pipeline (fully unrolled -> register renaming, no moves).
        if (r + 1 < ROWS_PER_WAVE) {
            #pragma unroll
            for (int k = 0; k < 8; ++k)
                cur[k] = nxt[k];
        }
    }
}

extern "C" void kernel_launch(void* const* d_in, const int* in_sizes, int n_in,
                              void* d_out, int out_size, void* d_ws, size_t ws_size,
                              hipStream_t stream) {
    const float* x     = (const float*)d_in[0];
    const float* exp_c = (const float*)d_in[1];
    const float* inv_c = (const float*)d_in[2];
    const int*   iters = (const int*)d_in[3];
    float* out = (float*)d_out;

    const int n_rows   = out_size / ROWLEN;                          // 32768
    const int n_blocks = n_rows / (WAVES_PER_BLOCK * ROWS_PER_WAVE); // 2048
    ckks_softmax_kernel<<<n_blocks, TPB, 0, stream>>>(x, exp_c, inv_c, iters, out);
}

// Round 3
// 442.535 us; speedup vs baseline: 1.0141x; 1.0141x over previous
//
#include <hip/hip_runtime.h>

// CKKS-style polynomial softmax over rows of 2048 fp32. x: [16, 2048, 2048].
// One WAVE per row-slot, 4 rows per wave (strided), register PING-PONG:
//   loadA(r0) loadB(r1) procA(r0) loadA(r2) procB(r1) loadB(r3) procA(r2) procB(r3)
// Each proc waits ONLY on its own buffer's 8 loads (vmcnt(8)/(16), never a
// full drain) -> every wave keeps a buffer's worth of loads in flight at all
// times. No rotation copies (round-2's cur=nxt forced vmcnt(0) per row).
// No LDS, no __syncthreads. Plain cached loads (L3 serves ~half the input,
// FETCH=134MB measured) and plain cached STORES (retire into L2/L3, write
// back asynchronously -- same store path as the 6.4 TB/s rocclr fill; the
// round-2 nontemporal stores forced the full 268MB write drain in-kernel).

typedef float v4f __attribute__((ext_vector_type(4)));

#define ROWLEN          2048
#define TPB             256
#define WPB             (TPB / 64)   // 4 waves per block
#define ROWS_PER_WAVE   4
// grid = 32768 rows / (4 waves * 4 rows) = 2048 blocks; 8192 waves = 1x machine.

__global__ __launch_bounds__(TPB) void ckks_softmax_kernel(
    const float* __restrict__ x,
    const float* __restrict__ exp_c,   // 9 coeffs, power basis
    const float* __restrict__ inv_c,   // 5 coeffs
    const int*   __restrict__ iters_p, // single int (==3)
    float* __restrict__ out)
{
    const int lane   = threadIdx.x & 63;
    const int wid    = blockIdx.x * WPB + (threadIdx.x >> 6);
    const int nwaves = gridDim.x * WPB;

    // Uniform coefficient loads -> SGPRs.
    const float c0 = exp_c[0], c1 = exp_c[1], c2 = exp_c[2], c3 = exp_c[3],
                c4 = exp_c[4], c5 = exp_c[5], c6 = exp_c[6], c7 = exp_c[7],
                c8 = exp_c[8];
    const float i0 = inv_c[0], i1 = inv_c[1], i2 = inv_c[2], i3 = inv_c[3],
                i4 = inv_c[4];
    const int iters = *iters_p;

    auto horner8 = [&](float t) -> float {
        float acc = c8;
        acc = fmaf(acc, t, c7);
        acc = fmaf(acc, t, c6);
        acc = fmaf(acc, t, c5);
        acc = fmaf(acc, t, c4);
        acc = fmaf(acc, t, c3);
        acc = fmaf(acc, t, c2);
        acc = fmaf(acc, t, c1);
        acc = fmaf(acc, t, c0);
        return acc;
    };

    auto loadrow = [&](v4f (&buf)[8], int row) {
        const v4f* __restrict__ src = (const v4f*)(x + (size_t)row * ROWLEN);
        #pragma unroll
        for (int k = 0; k < 8; ++k)
            buf[k] = src[lane + 64 * k];
    };

    auto procrow = [&](v4f (&buf)[8], int row) {
        // e = poly_exp(x); keep e resident; shallow partial-sum tree.
        v4f acc4 = {0.0f, 0.0f, 0.0f, 0.0f};
        #pragma unroll
        for (int k = 0; k < 8; ++k) {
            v4f e;
            e.x = horner8(buf[k].x);
            e.y = horner8(buf[k].y);
            e.z = horner8(buf[k].z);
            e.w = horner8(buf[k].w);
            buf[k] = e;
            acc4 += e;
        }
        float s = (acc4.x + acc4.y) + (acc4.z + acc4.w);

        // In-wave butterfly: every lane ends with the full row sum.
        #pragma unroll
        for (int off = 32; off > 0; off >>= 1)
            s += __shfl_xor(s, off, 64);

        // Initial reciprocal guess (degree-4 Horner), redundant per lane.
        float y = i4;
        y = fmaf(y, s, i3);
        y = fmaf(y, s, i2);
        y = fmaf(y, s, i1);
        y = fmaf(y, s, i0);

        // Newton-Raphson: y <- y * (2 - s*y).
        for (int i = 0; i < iters; ++i)
            y = y * (2.0f - s * y);

        // Scale and store through the cache (async writeback, fill-style).
        v4f* __restrict__ dst = (v4f*)(out + (size_t)row * ROWLEN);
        #pragma unroll
        for (int k = 0; k < 8; ++k)
            dst[lane + 64 * k] = buf[k] * y;
    };

    v4f A[8], B[8];
    const int r0 = wid;
    const int r1 = wid + nwaves;
    const int r2 = wid + 2 * nwaves;
    const int r3 = wid + 3 * nwaves;

    loadrow(A, r0);          // 8 loads in flight
    loadrow(B, r1);          // 16 in flight
    procrow(A, r0);          // waits vmcnt(8): B stays in flight
    loadrow(A, r2);          // refill A immediately after A's stores issue
    procrow(B, r1);          // waits only B's loads; A2 + stores in flight
    loadrow(B, r3);
    procrow(A, r2);
    procrow(B, r3);
}

extern "C" void kernel_launch(void* const* d_in, const int* in_sizes, int n_in,
                              void* d_out, int out_size, void* d_ws, size_t ws_size,
                              hipStream_t stream) {
    const float* x     = (const float*)d_in[0];
    const float* exp_c = (const float*)d_in[1];
    const float* inv_c = (const float*)d_in[2];
    const int*   iters = (const int*)d_in[3];
    float* out = (float*)d_out;

    const int n_rows   = out_size / ROWLEN;                    // 32768
    const int n_blocks = n_rows / (WPB * ROWS_PER_WAVE);       // 2048
    ckks_softmax_kernel<<<n_blocks, TPB, 0, stream>>>(x, exp_c, inv_c, iters, out);
}

// Round 4
// 438.978 us; speedup vs baseline: 1.0223x; 1.0081x over previous
//
#include <hip/hip_runtime.h>

// CKKS-style polynomial softmax over rows of 2048 fp32. x: [16, 2048, 2048].
// Round-4 structure: 2 rows per wave, register ping-pong, 2x machine
// oversubscription (16384 waves on 8192 wave slots).
//   loadA(r0); loadB(r1); procA; procB;
// - procA waits vmcnt(8): B's loads stay in flight under A's compute.
// - procB waits only on B's loads, which are OLDER than A's stores in the
//   in-order vmcnt queue -> no store-ack coupling (round-3's 4-row schedule
//   made waves wait behind their own stores).
// - 2x oversubscription: waves retire after 2 rows and are replaced, so the
//   scheduler load-balances across CUs/XCDs (round-3's exactly-1x grid had
//   zero slack and ran at the straggler's pace).
// - no LDS, no __syncthreads; row-sum is an in-wave shfl_xor butterfly.
// - plain cached loads AND stores (fill-style async writeback; measured
//   FETCH=134MB shows L3 serves ~half the input when cached).
// __launch_bounds__(256, 4): allow up to ~128 VGPRs (2x32 data regs + temps),
// 4 waves/SIMD -- don't let the compiler spill chasing 8 waves/SIMD.

typedef float v4f __attribute__((ext_vector_type(4)));

#define ROWLEN          2048
#define TPB             256
#define WPB             (TPB / 64)   // 4 waves per block
#define ROWS_PER_WAVE   2
// grid = 32768 / (4*2) = 4096 blocks = 16384 waves = 2x machine capacity.

__global__ __launch_bounds__(TPB, 4) void ckks_softmax_kernel(
    const float* __restrict__ x,
    const float* __restrict__ exp_c,   // 9 coeffs, power basis
    const float* __restrict__ inv_c,   // 5 coeffs
    const int*   __restrict__ iters_p, // single int (==3)
    float* __restrict__ out)
{
    const int lane   = threadIdx.x & 63;
    const int wid    = blockIdx.x * WPB + (threadIdx.x >> 6);
    const int nwaves = gridDim.x * WPB;          // 16384

    // Uniform coefficient loads -> SGPRs.
    const float c0 = exp_c[0], c1 = exp_c[1], c2 = exp_c[2], c3 = exp_c[3],
                c4 = exp_c[4], c5 = exp_c[5], c6 = exp_c[6], c7 = exp_c[7],
                c8 = exp_c[8];
    const float i0 = inv_c[0], i1 = inv_c[1], i2 = inv_c[2], i3 = inv_c[3],
                i4 = inv_c[4];
    const int iters = *iters_p;

    auto horner8 = [&](float t) -> float {
        float acc = c8;
        acc = fmaf(acc, t, c7);
        acc = fmaf(acc, t, c6);
        acc = fmaf(acc, t, c5);
        acc = fmaf(acc, t, c4);
        acc = fmaf(acc, t, c3);
        acc = fmaf(acc, t, c2);
        acc = fmaf(acc, t, c1);
        acc = fmaf(acc, t, c0);
        return acc;
    };

    auto loadrow = [&](v4f (&buf)[8], int row) {
        const v4f* __restrict__ src = (const v4f*)(x + (size_t)row * ROWLEN);
        #pragma unroll
        for (int k = 0; k < 8; ++k)
            buf[k] = src[lane + 64 * k];
    };

    auto procrow = [&](v4f (&buf)[8], int row) {
        // e = poly_exp(x); keep e resident; shallow partial-sum tree.
        v4f acc4 = {0.0f, 0.0f, 0.0f, 0.0f};
        #pragma unroll
        for (int k = 0; k < 8; ++k) {
            v4f e;
            e.x = horner8(buf[k].x);
            e.y = horner8(buf[k].y);
            e.z = horner8(buf[k].z);
            e.w = horner8(buf[k].w);
            buf[k] = e;
            acc4 += e;
        }
        float s = (acc4.x + acc4.y) + (acc4.z + acc4.w);

        // In-wave butterfly: every lane ends with the full row sum.
        #pragma unroll
        for (int off = 32; off > 0; off >>= 1)
            s += __shfl_xor(s, off, 64);

        // Initial reciprocal guess (degree-4 Horner), redundant per lane.
        float y = i4;
        y = fmaf(y, s, i3);
        y = fmaf(y, s, i2);
        y = fmaf(y, s, i1);
        y = fmaf(y, s, i0);

        // Newton-Raphson: y <- y * (2 - s*y).
        for (int i = 0; i < iters; ++i)
            y = y * (2.0f - s * y);

        // Scale and store through the cache (async writeback, fill-style).
        v4f* __restrict__ dst = (v4f*)(out + (size_t)row * ROWLEN);
        #pragma unroll
        for (int k = 0; k < 8; ++k)
            dst[lane + 64 * k] = buf[k] * y;
    };

    v4f A[8], B[8];
    const int r0 = wid;
    const int r1 = wid + nwaves;

    loadrow(A, r0);   // 8 loads in flight
    loadrow(B, r1);   // 16 in flight
    procrow(A, r0);   // waits vmcnt(8); B rides under A's compute
    procrow(B, r1);   // waits only B's loads (older than A's stores)
}

extern "C" void kernel_launch(void* const* d_in, const int* in_sizes, int n_in,
                              void* d_out, int out_size, void* d_ws, size_t ws_size,
                              hipStream_t stream) {
    const float* x     = (const float*)d_in[0];
    const float* exp_c = (const float*)d_in[1];
    const float* inv_c = (const float*)d_in[2];
    const int*   iters = (const int*)d_in[3];
    float* out = (float*)d_out;

    const int n_rows   = out_size / ROWLEN;                    // 32768
    const int n_blocks = n_rows / (WPB * ROWS_PER_WAVE);       // 4096
    ckks_softmax_kernel<<<n_blocks, TPB, 0, stream>>>(x, exp_c, inv_c, iters, out);
}

// Round 5
// 427.050 us; speedup vs baseline: 1.0509x; 1.0279x over previous
//
#include <hip/hip_runtime.h>

// CKKS-style polynomial softmax over rows of 2048 fp32. x: [16, 2048, 2048].
// Round-5 = the two independently-validated wins combined:
//  (1) NONTEMPORAL loads AND stores (R0->R1 was the only positive A/B in the
//      session ledger; cached paths R2-R4 all regressed). Mechanism: pure
//      HBM streams, no L2/L3 allocate churn against the harness poison fill.
//      The m13 float4-copy datum (6.29 TB/s, same 50/50 read+write mix)
//      proves stream-shaped mixed traffic runs at full rate.
//  (2) Clean 2-row register ping-pong (R4 structure): loadA, loadB, procA,
//      procB. procA waits vmcnt(8) with B's loads in flight; procB's loads
//      are OLDER than A's stores (no store coupling); no buffer refill
//      (R3's WAR-hazard drain). 2x machine oversubscription for rebalance.
//  Row pair is CONTIGUOUS: wave streams 16 KB sequential, block 64 KB.
//  No LDS, no __syncthreads; row-sum = in-wave shfl_xor butterfly.

typedef float v4f __attribute__((ext_vector_type(4)));

#define ROWLEN          2048
#define TPB             256
#define WPB             (TPB / 64)   // 4 waves per block
#define ROWS_PER_WAVE   2
// grid = 32768 / (4*2) = 4096 blocks = 16384 waves = 2x machine capacity.

__global__ __launch_bounds__(TPB, 4) void ckks_softmax_kernel(
    const float* __restrict__ x,
    const float* __restrict__ exp_c,   // 9 coeffs, power basis
    const float* __restrict__ inv_c,   // 5 coeffs
    const int*   __restrict__ iters_p, // single int (==3)
    float* __restrict__ out)
{
    const int lane = threadIdx.x & 63;
    const int wid  = blockIdx.x * WPB + (threadIdx.x >> 6);

    // Uniform coefficient loads -> SGPRs.
    const float c0 = exp_c[0], c1 = exp_c[1], c2 = exp_c[2], c3 = exp_c[3],
                c4 = exp_c[4], c5 = exp_c[5], c6 = exp_c[6], c7 = exp_c[7],
                c8 = exp_c[8];
    const float i0 = inv_c[0], i1 = inv_c[1], i2 = inv_c[2], i3 = inv_c[3],
                i4 = inv_c[4];
    const int iters = *iters_p;

    auto horner8 = [&](float t) -> float {
        float acc = c8;
        acc = fmaf(acc, t, c7);
        acc = fmaf(acc, t, c6);
        acc = fmaf(acc, t, c5);
        acc = fmaf(acc, t, c4);
        acc = fmaf(acc, t, c3);
        acc = fmaf(acc, t, c2);
        acc = fmaf(acc, t, c1);
        acc = fmaf(acc, t, c0);
        return acc;
    };

    auto loadrow = [&](v4f (&buf)[8], size_t row) {
        const v4f* __restrict__ src = (const v4f*)(x + row * ROWLEN);
        #pragma unroll
        for (int k = 0; k < 8; ++k)
            buf[k] = __builtin_nontemporal_load(&src[lane + 64 * k]);
    };

    auto procrow = [&](v4f (&buf)[8], size_t row) {
        // e = poly_exp(x); keep e resident; shallow partial-sum tree.
        v4f acc4 = {0.0f, 0.0f, 0.0f, 0.0f};
        #pragma unroll
        for (int k = 0; k < 8; ++k) {
            v4f e;
            e.x = horner8(buf[k].x);
            e.y = horner8(buf[k].y);
            e.z = horner8(buf[k].z);
            e.w = horner8(buf[k].w);
            buf[k] = e;
            acc4 += e;
        }
        float s = (acc4.x + acc4.y) + (acc4.z + acc4.w);

        // In-wave butterfly: every lane ends with the full row sum.
        #pragma unroll
        for (int off = 32; off > 0; off >>= 1)
            s += __shfl_xor(s, off, 64);

        // Initial reciprocal guess (degree-4 Horner), redundant per lane.
        float y = i4;
        y = fmaf(y, s, i3);
        y = fmaf(y, s, i2);
        y = fmaf(y, s, i1);
        y = fmaf(y, s, i0);

        // Newton-Raphson: y <- y * (2 - s*y).
        for (int i = 0; i < iters; ++i)
            y = y * (2.0f - s * y);

        // Scale and stream out (nontemporal: pure write stream to HBM).
        v4f* __restrict__ dst = (v4f*)(out + row * ROWLEN);
        #pragma unroll
        for (int k = 0; k < 8; ++k)
            __builtin_nontemporal_store(buf[k] * y, &dst[lane + 64 * k]);
    };

    v4f A[8], B[8];
    const size_t r0 = (size_t)wid * ROWS_PER_WAVE;   // contiguous pair
    const size_t r1 = r0 + 1;

    loadrow(A, r0);   // 8 loads in flight
    loadrow(B, r1);   // 16 in flight, 16 KB sequential per wave
    procrow(A, r0);   // waits vmcnt(8); B rides under A's compute
    procrow(B, r1);   // waits only B's loads (older than A's stores)
}

extern "C" void kernel_launch(void* const* d_in, const int* in_sizes, int n_in,
                              void* d_out, int out_size, void* d_ws, size_t ws_size,
                              hipStream_t stream) {
    const float* x     = (const float*)d_in[0];
    const float* exp_c = (const float*)d_in[1];
    const float* inv_c = (const float*)d_in[2];
    const int*   iters = (const int*)d_in[3];
    float* out = (float*)d_out;

    const int n_rows   = out_size / ROWLEN;                    // 32768
    const int n_blocks = n_rows / (WPB * ROWS_PER_WAVE);       // 4096
    ckks_softmax_kernel<<<n_blocks, TPB, 0, stream>>>(x, exp_c, inv_c, iters, out);
}